// Round 5
// baseline (252.015 us; speedup 1.0000x reference)
//
#include <hip/hip_runtime.h>
#include <hip/hip_fp16.h>

namespace {

constexpr int T_STEPS = 256;
constexpr int HD = 50;    // hidden size
constexpr int HP = 64;    // padded hidden
constexpr int KSTS = 72;  // weight staging stride
constexpr int BT = 16;    // batch tile per block
constexpr int NTHR = 192; // R16: 3 waves — one per layer, whole layer per wave
constexpr int XST = 34;   // xls row stride in floats
constexpr int NSLOT = 8;  // h ring slots per layer
constexpr int SLOT_SH = BT * 64;         // shorts per (layer, slot) = 1024
constexpr int LAY_SH = NSLOT * SLOT_SH;  // shorts per layer = 8192

typedef __attribute__((ext_vector_type(8))) _Float16 f16x8;
typedef __attribute__((ext_vector_type(4))) float f32x4;

__device__ __forceinline__ unsigned short f2h(float x) {
  __half h = __float2half(x);  // RNE
  return *reinterpret_cast<unsigned short*>(&h);
}
__device__ __forceinline__ float h2f(unsigned short u) {
  __half h;
  *reinterpret_cast<unsigned short*>(&h) = u;
  return __half2float(h);
}

#define MFMA16 __builtin_amdgcn_mfma_f32_16x16x32_f16

// R16: barrier-light restructure. R11..R15 showed the kernel is a
// barrier-locked latency chain: 260 per-step barriers force 12 lockstep
// waves whose stalls align (R13: -20% VALU = 0 time; R15: conflicts -5x =
// -9% time). The per-step barrier existed only because 4 sibling waves per
// layer exchange h every step. Here ONE wave owns a whole layer (50 rows x
// 16 batches): self-recurrence is wave-local (write h_t, read own B-frags
// back — same-wave DS FIFO ordering, NO barrier). Cross-layer uses a 4-step
// diagonal (L_ell lags 4*ell steps) -> one barrier per 4 steps (66 total),
// with the interval's 8 cross b128 reads deep-prefetched right after the
// barrier. 8-slot ring: slot t%8 written in interval t/4, cross-read in
// interval t/4+1, overwritten in t/4+2 — always barrier-separated.
// Carried over: R15 XOR granule swizzle (validated: conflicts -5x),
// R14 exact-x2 weight prescale (validated: tanh = 1 - 2/(exp(c')+1)).
__global__ __launch_bounds__(NTHR, 1) void rnn3_kernel(
    const float* __restrict__ x,
    const float* __restrict__ Wih1, const float* __restrict__ Whh1,
    const float* __restrict__ bih1, const float* __restrict__ bhh1,
    const float* __restrict__ Wih2, const float* __restrict__ Whh2,
    const float* __restrict__ bih2, const float* __restrict__ bhh2,
    const float* __restrict__ Wih3, const float* __restrict__ Whh3,
    const float* __restrict__ bih3, const float* __restrict__ bhh3,
    const float* __restrict__ fcw, const float* __restrict__ fcb,
    float* __restrict__ out) {
  __shared__ unsigned short hbuf[3 * LAY_SH];  // [layer][slot][n][swz k]
  __shared__ float xls[T_STEPS][XST];          // staged x
  __shared__ unsigned short scr[HP * KSTS];    // weight staging (fp16)

  const int tid = threadIdx.x;
  const int ell = tid >> 6;      // wave = layer 0..2
  const int lane = tid & 63;
  const int quad = lane >> 4;
  const int l15 = lane & 15;
  const int b0 = blockIdx.x * BT;

  // zero all ring slots (initial h=0 and the never-written k>=52 pad rows)
  {
    uint4* hz = reinterpret_cast<uint4*>(hbuf);
    const int n = 3 * LAY_SH * 2 / 16;
    for (int i = tid; i < n; i += NTHR) hz[i] = make_uint4(0u, 0u, 0u, 0u);
  }
  // stage x -> LDS
  for (int idx = tid; idx < BT * T_STEPS; idx += NTHR) {
    int b = idx >> 8, t = idx & 255;
    float2 v = *reinterpret_cast<const float2*>(x + (size_t)(b0 + b) * (T_STEPS * 2) + 2 * t);
    xls[t][2 * b] = v.x;
    xls[t][2 * b + 1] = v.y;
  }

  // ---- stage the five 50x50 matrices as fp16, pre-scaled by exactly 2 ----
  const float* mats[5] = {Whh1, Wih2, Whh2, Wih3, Whh3};
  constexpr int matL[5] = {0, 1, 1, 2, 2};
  constexpr int matS[5] = {1, 0, 1, 0, 1};  // 1 = self (Whh), 0 = cross (Wih)
  f16x8 wS[4][2], wC[4][2];  // A-frags: [M-tile][kstep]
#pragma unroll
  for (int mt = 0; mt < 4; ++mt)
#pragma unroll
    for (int ks = 0; ks < 2; ++ks) { wS[mt][ks] = f16x8(0); wC[mt][ks] = f16x8(0); }

#pragma unroll
  for (int m = 0; m < 5; ++m) {
    __syncthreads();
    const float* W = mats[m];
    for (int idx = tid; idx < HP * HP; idx += NTHR) {
      int i = idx >> 6, k = idx & 63;
      float v = (i < HD && k < HD) ? 2.0f * W[i * HD + k] : 0.0f;  // exact x2
      scr[i * KSTS + k] = f2h(v);
    }
    __syncthreads();
    if (ell == matL[m]) {
#pragma unroll
      for (int mt = 0; mt < 4; ++mt) {
        const unsigned short* ph = &scr[(16 * mt + l15) * KSTS + 8 * quad];
        f16x8 a0 = *reinterpret_cast<const f16x8*>(ph);
        f16x8 a1 = *reinterpret_cast<const f16x8*>(ph + 32);
        if (matS[m]) { wS[mt][0] = a0; wS[mt][1] = a1; }
        else         { wC[mt][0] = a0; wC[mt][1] = a1; }
      }
    }
  }

  // per-lane C-row constants (pre-scaled by 2)
  const float* bi = (ell == 0) ? bih1 : (ell == 1) ? bih2 : bih3;
  const float* bh = (ell == 0) ? bhh1 : (ell == 1) ? bhh2 : bhh3;
  f32x4 bsv[4];
  float wx0[4][4], wx1[4][4];
#pragma unroll
  for (int mt = 0; mt < 4; ++mt)
#pragma unroll
    for (int r = 0; r < 4; ++r) {
      int i = 16 * mt + 4 * quad + r;
      bool v = i < HD;
      bsv[mt][r] = v ? 2.0f * (bi[i] + bh[i]) : 0.0f;
      wx0[mt][r] = (v && ell == 0) ? 2.0f * Wih1[i * 2 + 0] : 0.0f;
      wx1[mt][r] = (v && ell == 0) ? 2.0f * Wih1[i * 2 + 1] : 0.0f;
    }

  // B-frag read offsets (R15 swizzle: granule g at row n lives at g^(n&7))
  const int off0 = l15 * 64 + ((quad ^ (l15 & 7)) << 3);
  const int off1 = off0 ^ 32;  // kstep1 granule = g0^4 -> byte bit-5 flip
  const unsigned short* sbB = hbuf + ell * LAY_SH;                      // self
  const unsigned short* cbB = hbuf + ((ell > 0) ? ell - 1 : 0) * LAY_SH;  // cross
  unsigned short* hb = hbuf + ell * LAY_SH;

  // swizzled write offsets per M-tile: rows ic..ic+3 at batch n=l15
  int wofs[4];
#pragma unroll
  for (int mt = 0; mt < 4; ++mt) {
    int ic = 16 * mt + 4 * quad;
    wofs[mt] = l15 * 64 + ((((ic >> 3) ^ (l15 & 7))) << 3) + (ic & 7);
  }

  f16x8 bS0 = f16x8(0), bS1 = f16x8(0);  // self B (h_{t-1}); h_{-1} = 0
  f16x8 pf0[4], pf1[4];                  // deep-prefetched cross B for 4 steps
  float2 xq[4];                          // prefetched x (L0)
#pragma unroll
  for (int j = 0; j < 4; ++j) { pf0[j] = f16x8(0); pf1[j] = f16x8(0); xq[j] = make_float2(0.f, 0.f); }

  // ---- main loop: 66 intervals x 4 steps; ONE barrier per interval ----
  for (int I = 0; I < 66; ++I) {
    __syncthreads();  // cross-layer visibility for the previous interval
    const int Ip = I - ell;               // this wave's local interval
    if ((unsigned)Ip >= 64u) continue;    // inactive: barrier only
    const int half = (Ip & 1) * (4 * SLOT_SH);  // slot (4*Ip+j)%8 = half/1024 + j

    // deep prefetch: whole interval's cross fragments (written last interval)
    if (ell > 0) {
#pragma unroll
      for (int j = 0; j < 4; ++j) {
        pf0[j] = *reinterpret_cast<const f16x8*>(cbB + half + j * SLOT_SH + off0);
        pf1[j] = *reinterpret_cast<const f16x8*>(cbB + half + j * SLOT_SH + off1);
      }
    } else {
      const int t0 = 4 * Ip;
#pragma unroll
      for (int j = 0; j < 4; ++j)
        xq[j] = *reinterpret_cast<const float2*>(&xls[t0 + j][2 * l15]);
    }

#pragma unroll
    for (int j = 0; j < 4; ++j) {
      const int sofs = half + j * SLOT_SH;
      f32x4 cm[4];
      if (ell == 0) {
#pragma unroll
        for (int mt = 0; mt < 4; ++mt) {
          f32x4 ci;
#pragma unroll
          for (int r = 0; r < 4; ++r)
            ci[r] = fmaf(wx1[mt][r], xq[j].y, fmaf(wx0[mt][r], xq[j].x, bsv[mt][r]));
          f32x4 c = MFMA16(wS[mt][0], bS0, ci, 0, 0, 0);
          cm[mt] = MFMA16(wS[mt][1], bS1, c, 0, 0, 0);
        }
      } else {
        // self first (bS ready from last step's read-back), cross second
        // (gives the post-barrier prefetch time to land at j=0)
#pragma unroll
        for (int mt = 0; mt < 4; ++mt) {
          f32x4 c = MFMA16(wS[mt][0], bS0, bsv[mt], 0, 0, 0);
          c = MFMA16(wS[mt][1], bS1, c, 0, 0, 0);
          c = MFMA16(wC[mt][0], pf0[j], c, 0, 0, 0);
          cm[mt] = MFMA16(wC[mt][1], pf1[j], c, 0, 0, 0);
        }
      }
      // tanh(c) = 1 - 2/(exp(c')+1), c' = 2c via pre-scaled weights.
      // clamp +-22 keeps the 4-value product < f32-max (validated in R14).
#pragma unroll
      for (int mt = 0; mt < 3; ++mt) {
        float d[4];
#pragma unroll
        for (int r = 0; r < 4; ++r) {
          float xr = __builtin_amdgcn_fmed3f(cm[mt][r], -22.0f, 22.0f);
          d[r] = __expf(xr) + 1.0f;
        }
        float p01 = d[0] * d[1], p23 = d[2] * d[3];
        float rp = __builtin_amdgcn_rcpf(p01 * p23);
        float q01 = rp * p23, q23 = rp * p01;
        unsigned short t0 = f2h(fmaf(-2.0f, q01 * d[1], 1.0f));
        unsigned short t1 = f2h(fmaf(-2.0f, q01 * d[0], 1.0f));
        unsigned short t2 = f2h(fmaf(-2.0f, q23 * d[3], 1.0f));
        unsigned short t3 = f2h(fmaf(-2.0f, q23 * d[2], 1.0f));
        *reinterpret_cast<uint2*>(hb + sofs + wofs[mt]) =
            make_uint2((unsigned)t0 | ((unsigned)t1 << 16),
                       (unsigned)t2 | ((unsigned)t3 << 16));
      }
      {  // tile 3: rows 48,49 live (quad0 r0/r1); rows 50,51 written 0;
         // rows 52..63 never written (keep init zeros forever).
        float x0 = __builtin_amdgcn_fmed3f(cm[3][0], -22.0f, 22.0f);
        float x1 = __builtin_amdgcn_fmed3f(cm[3][1], -22.0f, 22.0f);
        float d0 = __expf(x0) + 1.0f;
        float d1 = __expf(x1) + 1.0f;
        float rp = __builtin_amdgcn_rcpf(d0 * d1);
        unsigned short t0 = f2h(fmaf(-2.0f, rp * d1, 1.0f));
        unsigned short t1 = f2h(fmaf(-2.0f, rp * d0, 1.0f));
        if (quad == 0) {
          *reinterpret_cast<uint2*>(hb + sofs + wofs[3]) =
              make_uint2((unsigned)t0 | ((unsigned)t1 << 16), 0u);
        }
      }
      // self read-back for the NEXT step: same wave just wrote this slot —
      // DS pipe FIFO gives RAW; consumed only after next step's MFMA wait.
      bS0 = *reinterpret_cast<const f16x8*>(sbB + sofs + off0);
      bS1 = *reinterpret_cast<const f16x8*>(sbB + sofs + off1);
    }
  }

  __syncthreads();
  // ---- fc epilogue: h3_255 lives in layer-2 slot 255%8 = 7 ----
  if (tid < BT * 2) {
    int b = tid >> 1, o = tid & 1;
    const unsigned short* h3 = hbuf + 2 * LAY_SH + 7 * SLOT_SH + b * 64;
    float acc = fcb[o];
    for (int i = 0; i < HD; ++i) {
      int sw = (((i >> 3) ^ (b & 7)) << 3) + (i & 7);  // swizzled column
      acc += fcw[o * HD + i] * h2f(h3[sw]);
    }
    out[(size_t)(b0 + b) * 2 + o] = acc;
  }
}

}  // namespace

extern "C" void kernel_launch(void* const* d_in, const int* in_sizes, int n_in,
                              void* d_out, int out_size, void* d_ws, size_t ws_size,
                              hipStream_t stream) {
  const float* x = (const float*)d_in[0];
  const float* Wih1 = (const float*)d_in[1];
  const float* Whh1 = (const float*)d_in[2];
  const float* bih1 = (const float*)d_in[3];
  const float* bhh1 = (const float*)d_in[4];
  const float* Wih2 = (const float*)d_in[5];
  const float* Whh2 = (const float*)d_in[6];
  const float* bih2 = (const float*)d_in[7];
  const float* bhh2 = (const float*)d_in[8];
  const float* Wih3 = (const float*)d_in[9];
  const float* Whh3 = (const float*)d_in[10];
  const float* bih3 = (const float*)d_in[11];
  const float* bhh3 = (const float*)d_in[12];
  const float* fcw = (const float*)d_in[13];
  const float* fcb = (const float*)d_in[14];

  rnn3_kernel<<<4096 / BT, NTHR, 0, stream>>>(x, Wih1, Whh1, bih1, bhh1,
                                              Wih2, Whh2, bih2, bhh2,
                                              Wih3, Whh3, bih3, bhh3,
                                              fcw, fcb, (float*)d_out);
}

// Round 6
// 237.636 us; speedup vs baseline: 1.0605x; 1.0605x over previous
//
#include <hip/hip_runtime.h>
#include <hip/hip_fp16.h>

namespace {

constexpr int T_STEPS = 256;
constexpr int HD = 50;    // hidden size
constexpr int HP = 64;    // padded hidden
constexpr int KST = 64;   // h-buf row stride in fp16 elems (R15 swizzle layout)
constexpr int KSTS = 72;  // weight staging stride
constexpr int BT = 8;     // R17: REAL batches per block (grid doubled)
constexpr int BTP = 16;   // padded batch rows in LDS layout (MFMA N=16)
constexpr int NTHR = 768; // 12 waves: (layer, M-tile)
constexpr int XST = 34;   // xls row stride in floats (16-batch layout kept)
constexpr int LAY_SH = BTP * KST;    // shorts per (slot, layer)
constexpr int SLOT_SH = 3 * LAY_SH;  // shorts per ring slot

typedef __attribute__((ext_vector_type(8))) _Float16 f16x8;
typedef __attribute__((ext_vector_type(4))) float f32x4;

__device__ __forceinline__ unsigned short f2h(float x) {
  __half h = __float2half(x);  // RNE
  return *reinterpret_cast<unsigned short*>(&h);
}
__device__ __forceinline__ float h2f(unsigned short u) {
  __half h;
  *reinterpret_cast<unsigned short*>(&h) = u;
  return __half2float(h);
}

#define MFMA16 __builtin_amdgcn_mfma_f32_16x16x32_f16

// Raw workgroup barrier WITHOUT the lgkmcnt(0) drain that __syncthreads emits.
// Safe: DS ops enter the CU's LDS pipe at ISSUE in program order; consumer
// reads issue only after barrier release, i.e. after producers' writes are
// enqueued; per-bank FIFO processing gives RAW visibility. (HW-validated.)
__device__ __forceinline__ void barrier_nodrain() {
  asm volatile("s_barrier" ::: "memory");
}

// R17 = R15 (12-wave layer x M-tile + XOR-swizzled hbuf) split into TWO
// co-resident blocks per CU. Budget from R11..R16: step = 1100cy of which
// LDS-pipe service ~580cy (45 wave-ops x ~12cy b128, pipe 53% busy) and
// ~400-500cy is phase-collision stall (barrier-locked waves read together,
// then tanh together). A second independent block on the CU fills those
// stalls: its LDS phase overlaps this block's VALU phase -> pipe ~100%
// utilized, per-16-batch step cost -> ~580-700cy. Per-wave LDS op count is
// batch-count-independent (wave-wide b128s), so BT 16->8 + grid x2 keeps
// per-block cost identical while doubling blocks/CU.
// LDS layout (hbuf/xls) kept at 16-batch padding: block size 62464B ->
// exactly 2 blocks/CU (125KB<160KB), 24 waves = 6/SIMD, VGPR 40 <= 85.
// Pad batches (l15>=8): xls zeroed -> h_pad = tanh(bias), finite, and MFMA
// column isolation keeps them out of real columns. fc writes 8 rows.
__global__ __launch_bounds__(NTHR, 6) void rnn3_kernel(
    const float* __restrict__ x,
    const float* __restrict__ Wih1, const float* __restrict__ Whh1,
    const float* __restrict__ bih1, const float* __restrict__ bhh1,
    const float* __restrict__ Wih2, const float* __restrict__ Whh2,
    const float* __restrict__ bih2, const float* __restrict__ bhh2,
    const float* __restrict__ Wih3, const float* __restrict__ Whh3,
    const float* __restrict__ bih3, const float* __restrict__ bhh3,
    const float* __restrict__ fcw, const float* __restrict__ fcb,
    float* __restrict__ out) {
  __shared__ unsigned short hbuf[3 * SLOT_SH];  // [ring][layer][swizzled b,k]
  __shared__ float xls[T_STEPS][XST];           // staged x (cols >=2*BT zero)
  __shared__ unsigned short scr[HP * KSTS];     // weight staging (fp16)

  const int tid = threadIdx.x;
  const int w = tid >> 6;
  const int myL = w >> 2;        // layer 0..2
  const int wv = w & 3;          // M-tile
  const int lane = tid & 63;
  const int quad = lane >> 4;
  const int l15 = lane & 15;
  const int b0 = blockIdx.x * BT;

  // zero all 3 ring slots (initial h=0 and the k>=HD / batch>=BT pad)
  {
    unsigned int* hz = reinterpret_cast<unsigned int*>(hbuf);
    const int n = 3 * SLOT_SH / 2;
    for (int i = tid; i < n; i += NTHR) hz[i] = 0u;
  }
  // stage x -> LDS; batch rows >= BT get zeros (pad lanes read them)
  for (int idx = tid; idx < BTP * T_STEPS; idx += NTHR) {
    int b = idx >> 8, t = idx & 255;
    float2 v = make_float2(0.0f, 0.0f);
    if (b < BT)
      v = *reinterpret_cast<const float2*>(x + (size_t)(b0 + b) * (T_STEPS * 2) + 2 * t);
    xls[t][2 * b] = v.x;
    xls[t][2 * b + 1] = v.y;
  }

  // ---- stage the five 50x50 matrices as fp16 ----
  const float* mats[5] = {Whh1, Wih2, Whh2, Wih3, Whh3};
  constexpr int matL[5] = {0, 1, 1, 2, 2};
  constexpr int matS[5] = {0, 0, 1, 0, 1};  // slot0 = cross (self for L0), slot1 = self
  f16x8 wA[2][2];  // [slot][kstep]
#pragma unroll
  for (int sl = 0; sl < 2; ++sl)
#pragma unroll
    for (int ks = 0; ks < 2; ++ks) wA[sl][ks] = f16x8(0);

  const int arow = 16 * wv + l15;
#pragma unroll
  for (int m = 0; m < 5; ++m) {
    __syncthreads();
    const float* W = mats[m];
    for (int idx = tid; idx < HP * HP; idx += NTHR) {
      int i = idx >> 6, k = idx & 63;
      float v = (i < HD && k < HD) ? W[i * HD + k] : 0.0f;
      scr[i * KSTS + k] = f2h(v);
    }
    __syncthreads();
    if (myL == matL[m]) {
      const int sl = matS[m];
      const unsigned short* ph = &scr[arow * KSTS + 8 * quad];
      wA[sl][0] = *reinterpret_cast<const f16x8*>(ph);
      wA[sl][1] = *reinterpret_cast<const f16x8*>(ph + 32);
    }
  }

  // per-lane C-row constants
  const int ic = 16 * wv + 4 * quad;
  const float* bi = (myL == 0) ? bih1 : (myL == 1) ? bih2 : bih3;
  const float* bh = (myL == 0) ? bhh1 : (myL == 1) ? bhh2 : bhh3;
  float wx0[4], wx1[4];
  f32x4 bsv;
#pragma unroll
  for (int r = 0; r < 4; ++r) {
    int i = ic + r;
    bool v = i < HD;
    bsv[r] = v ? (bi[i] + bh[i]) : 0.0f;
    wx0[r] = (v && myL == 0) ? Wih1[i * 2 + 0] : 0.0f;
    wx1[r] = (v && myL == 0) ? Wih1[i * 2 + 1] : 0.0f;
  }

  const int selfBuf = myL;
  const int crossBuf = (myL > 0) ? myL - 1 : 0;

  // Swizzled read offsets: granule for quad Q is Q^(l15&7); the +32 partner
  // (granule Q+4) is a pure bit-5 flip of the short offset.
  const int off0 = l15 * KST + ((quad ^ (l15 & 7)) << 3);
  const int off1 = off0 ^ 32;
  const unsigned short* sb = hbuf + selfBuf * LAY_SH;
  const unsigned short* cb = hbuf + crossBuf * LAY_SH;

  // Swizzled write base: cols ic..ic+3 sit inside granule ic>>3 (ic % 4 == 0).
  unsigned short* wbase = hbuf + myL * LAY_SH + l15 * KST +
                          (((ic >> 3) ^ (l15 & 7)) << 3) + (ic & 7);

  f16x8 pfC0 = f16x8(0), pfC1 = f16x8(0);  // cross B-frags for CURRENT step
  float2 xpf;                              // x for CURRENT step (L0)

  __syncthreads();
  xpf = *reinterpret_cast<const float2*>(&xls[0][2 * l15]);

  // ---- compute core for one diagonal step ----
  // Self reads post-barrier (siblings wrote them this interval). Cross/x
  // prefetch for s+1 at the END (slot rd holds data written before the
  // PREVIOUS barrier -> race-free, lands in the tanh phase).
  auto core = [&](int s, int wr, int rd) {
    f16x8 bS0 = *reinterpret_cast<const f16x8*>(sb + rd * SLOT_SH + off0);
    f16x8 bS1 = *reinterpret_cast<const f16x8*>(sb + rd * SLOT_SH + off1);
    f32x4 c;
    if (myL == 0) {
      f32x4 ci;
#pragma unroll
      for (int r = 0; r < 4; ++r) ci[r] = fmaf(wx1[r], xpf.y, fmaf(wx0[r], xpf.x, bsv[r]));
      c = MFMA16(wA[0][0], bS0, ci, 0, 0, 0);
      c = MFMA16(wA[0][1], bS1, c, 0, 0, 0);
    } else {
      // cross MFMAs first: operands register-resident (prefetched), run
      // while the self ds_reads above are still in flight.
      c = MFMA16(wA[0][0], pfC0, bsv, 0, 0, 0);
      c = MFMA16(wA[0][1], pfC1, c, 0, 0, 0);
      c = MFMA16(wA[1][0], bS0, c, 0, 0, 0);
      c = MFMA16(wA[1][1], bS1, c, 0, 0, 0);
    }
    if (wv != 3) {
      // batched tanh: ONE rcp for 4 values; clamp keeps product < f32-max
      float d[4];
#pragma unroll
      for (int r = 0; r < 4; ++r) {
        float xr = __builtin_amdgcn_fmed3f(c[r], -11.0f, 11.0f);
        d[r] = __expf(2.0f * xr) + 1.0f;
      }
      float p01 = d[0] * d[1], p23 = d[2] * d[3];
      float rp = __builtin_amdgcn_rcpf(p01 * p23);
      float q01 = rp * p23, q23 = rp * p01;
      float iv[4] = {q01 * d[1], q01 * d[0], q23 * d[3], q23 * d[2]};
      unsigned short ht[4];
#pragma unroll
      for (int r = 0; r < 4; ++r) ht[r] = f2h(fmaf(-2.0f, iv[r], 1.0f));
      unsigned int h01 = (unsigned int)ht[0] | ((unsigned int)ht[1] << 16);
      unsigned int h23 = (unsigned int)ht[2] | ((unsigned int)ht[3] << 16);
      *reinterpret_cast<uint2*>(wbase + wr * SLOT_SH) = make_uint2(h01, h23);
    } else {
      // rows 48..63: only 48,49 live (quad0 r0/r1); rows >=50 are exactly 0
      // (zero A-rows + zero bias) and keep their one-time init zeros.
      float x0 = __builtin_amdgcn_fmed3f(c[0], -11.0f, 11.0f);
      float x1 = __builtin_amdgcn_fmed3f(c[1], -11.0f, 11.0f);
      float d0 = __expf(2.0f * x0) + 1.0f;
      float d1 = __expf(2.0f * x1) + 1.0f;
      float rp = __builtin_amdgcn_rcpf(d0 * d1);
      unsigned short t0 = f2h(fmaf(-2.0f, rp * d1, 1.0f));
      unsigned short t1 = f2h(fmaf(-2.0f, rp * d0, 1.0f));
      if (quad == 0) {
        *reinterpret_cast<uint2*>(wbase + wr * SLOT_SH) =
            make_uint2((unsigned)t0 | ((unsigned)t1 << 16), 0u);
      }
    }
    // end-of-core prefetch for step s+1 (slot rd == (s-1)%3: safe pre-barrier)
    if (myL > 0) {
      pfC0 = *reinterpret_cast<const f16x8*>(cb + rd * SLOT_SH + off0);
      pfC1 = *reinterpret_cast<const f16x8*>(cb + rd * SLOT_SH + off1);
    } else {
      xpf = *reinterpret_cast<const float2*>(&xls[(s + 1) & 255][2 * l15]);
    }
  };

  auto actOf = [&](int s) {
    return (myL == 0) ? (s < T_STEPS)
         : (myL == 1) ? (s >= 2 && s < T_STEPS + 2)
                      : (s >= 4);
  };

  // barrier-mode step (prologue/epilogue): full __syncthreads for safety.
  // Inactive waves still prefetch to keep pfC current for their first step.
  auto stepB = [&](int s, int wr, int rd, bool act) {
    if (act) {
      core(s, wr, rd);
    } else if (myL > 0) {
      pfC0 = *reinterpret_cast<const f16x8*>(cb + rd * SLOT_SH + off0);
      pfC1 = *reinterpret_cast<const f16x8*>(cb + rd * SLOT_SH + off1);
    }
    __syncthreads();
  };

  // prologue s=0..3
  for (int s = 0; s < 4; ++s) stepB(s, s % 3, (s + 2) % 3, actOf(s));
  // steady s=4..255: all waves active; literal ring slots; NO-DRAIN barrier
  for (int sbi = 4; sbi < 256; sbi += 3) {
    core(sbi + 0, 1, 0); barrier_nodrain();
    core(sbi + 1, 2, 1); barrier_nodrain();
    core(sbi + 2, 0, 2); barrier_nodrain();
  }
  __syncthreads();  // re-establish full ordering before act-gated epilogue
  // epilogue s=256..259
  for (int s = 256; s < 260; ++s) stepB(s, s % 3, (s + 2) % 3, actOf(s));

  // ---- fc epilogue: h3_255 written at s=259 -> slot 259%3 = 1 ----
  if (tid < BT * 2) {
    int b = tid >> 1, o = tid & 1;
    const unsigned short* h3 = hbuf + 1 * SLOT_SH + 2 * LAY_SH + b * KST;
    float acc = fcb[o];
    for (int i = 0; i < HD; ++i) {
      int sw = (((i >> 3) ^ (b & 7)) << 3) + (i & 7);  // swizzled column
      acc += fcw[o * HD + i] * h2f(h3[sw]);
    }
    out[(size_t)(b0 + b) * 2 + o] = acc;
  }
}

}  // namespace

extern "C" void kernel_launch(void* const* d_in, const int* in_sizes, int n_in,
                              void* d_out, int out_size, void* d_ws, size_t ws_size,
                              hipStream_t stream) {
  const float* x = (const float*)d_in[0];
  const float* Wih1 = (const float*)d_in[1];
  const float* Whh1 = (const float*)d_in[2];
  const float* bih1 = (const float*)d_in[3];
  const float* bhh1 = (const float*)d_in[4];
  const float* Wih2 = (const float*)d_in[5];
  const float* Whh2 = (const float*)d_in[6];
  const float* bih2 = (const float*)d_in[7];
  const float* bhh2 = (const float*)d_in[8];
  const float* Wih3 = (const float*)d_in[9];
  const float* Whh3 = (const float*)d_in[10];
  const float* bih3 = (const float*)d_in[11];
  const float* bhh3 = (const float*)d_in[12];
  const float* fcw = (const float*)d_in[13];
  const float* fcb = (const float*)d_in[14];

  rnn3_kernel<<<4096 / BT, NTHR, 0, stream>>>(x, Wih1, Whh1, bih1, bhh1,
                                              Wih2, Whh2, bih2, bhh2,
                                              Wih3, Whh3, bih3, bhh3,
                                              fcw, fcb, (float*)d_out);
}